// Round 9
// baseline (343.017 us; speedup 1.0000x reference)
//
#include <hip/hip_runtime.h>
#include <hip/hip_bf16.h>

#define INV_SQRT2 0.7071067811865475f

typedef __attribute__((ext_vector_type(8))) short short8;
typedef __attribute__((ext_vector_type(4))) float f32x4;

static __device__ __forceinline__ unsigned short f2bf(float f) {
  __hip_bfloat16 h = __float2bfloat16(f);
  return *(unsigned short*)&h;
}
static __device__ __forceinline__ float bfbits2f(unsigned int u16) {
  return __uint_as_float(u16 << 16);
}

// ---------- prep: bf16 copies of x + weights (+ legacy f32 k-major WT) ----------
__global__ __launch_bounds__(256) void prep_kernel(
    const float* __restrict__ x, const float* __restrict__ W_edge,
    const float* __restrict__ W_nn, const float* __restrict__ W_res,
    float* __restrict__ WT, unsigned short* __restrict__ Web,
    unsigned short* __restrict__ Wnb, unsigned short* __restrict__ Wrb,
    unsigned short* __restrict__ xb, int NX) {
  int idx = blockIdx.x * 256 + threadIdx.x;
  if (idx < NX) xb[idx] = f2bf(x[idx]);
  if (idx < 8192) Web[idx] = f2bf(W_edge[idx]);
  if (idx < 16384) {
    Wnb[idx] = f2bf(W_nn[idx]);
    Wrb[idx] = f2bf(W_res[idx]);
    int o = idx >> 7, k = idx & 127;
    WT[k * 128 + o] = W_nn[idx];
    WT[16384 + k * 128 + o] = W_res[idx];
  }
}

// ---------- dual histogram: cnt[0..N) = src counts, cnt[N..2N) = dst counts ----------
__global__ __launch_bounds__(256) void hist2_kernel(const int* __restrict__ ei,
                                                    int* cnt, int E, int N) {
  int e = blockIdx.x * 256 + threadIdx.x;
  if (e < E) {
    atomicAdd(&cnt[ei[e]], 1);
    atomicAdd(&cnt[N + ei[E + e]], 1);
  }
}

__global__ __launch_bounds__(256) void scan1_kernel(const int* __restrict__ cnt,
                                                    int* off, int* bsum, int N) {
  __shared__ int s[256];
  const int tid = threadIdx.x;
  const int gid = blockIdx.x * 256 + tid;
  const int v = (gid < N) ? cnt[gid] : 0;
  s[tid] = v;
  for (int o = 1; o < 256; o <<= 1) {
    __syncthreads();
    int t = (tid >= o) ? s[tid - o] : 0;
    __syncthreads();
    s[tid] += t;
  }
  if (gid < N) off[gid] = s[tid] - v;
  if (tid == 255) bsum[blockIdx.x] = s[255];
}

__global__ __launch_bounds__(512) void scan2_kernel(int* bsum, int nb) {
  __shared__ int s[512];
  const int tid = threadIdx.x;
  const int v = (tid < nb) ? bsum[tid] : 0;
  s[tid] = v;
  for (int o = 1; o < 512; o <<= 1) {
    __syncthreads();
    int t = (tid >= o) ? s[tid - o] : 0;
    __syncthreads();
    s[tid] += t;
  }
  if (tid < nb) bsum[tid] = s[tid] - v;
}

__global__ __launch_bounds__(256) void scan3_kernel(int* off, int* cur,
                                                    const int* __restrict__ bsum,
                                                    int N) {
  int gid = blockIdx.x * 256 + threadIdx.x;
  if (gid < N) {
    int v = off[gid] + bsum[blockIdx.x];
    off[gid] = v;
    cur[gid] = v;
  }
}

// ---------- bscatter: attr (bf16) + (src, dst-slot) -> src-sorted slots ----------
// 4 lanes per edge; random full-line writes (fire-and-forget).
__global__ __launch_bounds__(256) void bscatter_kernel(
    const int* __restrict__ ei, int* cur, const float* __restrict__ attr,
    unsigned short* __restrict__ attr_s, uint2* __restrict__ sd_s, int E, int N) {
  const int tid = threadIdx.x;
  const int j = tid >> 2, c = tid & 3;
  const int e = blockIdx.x * 64 + j;
  if (e >= E) return;
  const int src = ei[e];
  int ps = 0, pd = 0;
  if (c == 0) {
    ps = atomicAdd(&cur[src], 1);
    pd = atomicAdd(&cur[N + ei[E + e]], 1);
  }
  const int bl = (tid & 63) & ~3;   // broadcast from the group's c==0 lane
  ps = __shfl(ps, bl);
  pd = __shfl(pd, bl);
  const float* sp = attr + (size_t)e * 64 + c * 16;
  const float4 q0 = *(const float4*)(sp + 0);
  const float4 q1 = *(const float4*)(sp + 4);
  const float4 q2 = *(const float4*)(sp + 8);
  const float4 q3 = *(const float4*)(sp + 12);
  short8 a, b;
  a[0] = (short)f2bf(q0.x); a[1] = (short)f2bf(q0.y);
  a[2] = (short)f2bf(q0.z); a[3] = (short)f2bf(q0.w);
  a[4] = (short)f2bf(q1.x); a[5] = (short)f2bf(q1.y);
  a[6] = (short)f2bf(q1.z); a[7] = (short)f2bf(q1.w);
  b[0] = (short)f2bf(q2.x); b[1] = (short)f2bf(q2.y);
  b[2] = (short)f2bf(q2.z); b[3] = (short)f2bf(q2.w);
  b[4] = (short)f2bf(q3.x); b[5] = (short)f2bf(q3.y);
  b[6] = (short)f2bf(q3.z); b[7] = (short)f2bf(q3.w);
  *(short8*)&attr_s[(size_t)ps * 64 + c * 16 + 0] = a;
  *(short8*)&attr_s[(size_t)ps * 64 + c * 16 + 8] = b;
  if (c == 0) sd_s[ps] = make_uint2((unsigned)src, (unsigned)pd);
}

// ---------- msg: src-sorted slots (seq attr_s, clustered x) -> dst-slot write ----------
__global__ __launch_bounds__(256) void msg_mfma_kernel(
    const unsigned short* __restrict__ xb, const uint2* __restrict__ sd_s,
    const unsigned short* __restrict__ attr_s, const unsigned short* __restrict__ Web,
    unsigned short* __restrict__ msg, int E) {
  const int lane = threadIdx.x & 63;
  const int l15 = lane & 15;
  const int l4 = lane >> 4;
  const int t = (blockIdx.x * 256 + threadIdx.x) >> 6;   // one 16-slot tile per wave
  const int ntiles = (E + 15) >> 4;
  if (t >= ntiles) return;
  const int p0 = t * 16 + l15;
  const int p = (p0 < E) ? p0 : (E - 1);
  const uint2 sd = sd_s[p];
  const int src = (int)sd.x;
  const int pd = (int)sd.y;
  // x-row reads: src ids are sorted -> clustered / L1-L2 resident
  ushort4 xr[8];
  #pragma unroll
  for (int m = 0; m < 8; ++m)
    xr[m] = *(const ushort4*)&xb[(size_t)src * 128 + m * 16 + l4 * 4];
  // attr B-frags: fully sequential bf16
  const short8 bs0 = *(const short8*)&attr_s[(size_t)p * 64 + l4 * 8];
  const short8 bs1 = *(const short8*)&attr_s[(size_t)p * 64 + 32 + l4 * 8];
  f32x4 acc[8];
  #pragma unroll
  for (int m = 0; m < 8; ++m) acc[m] = (f32x4){0.f, 0.f, 0.f, 0.f};
  #pragma unroll
  for (int m = 0; m < 8; ++m) {
    const short8 af0 = *(const short8*)&Web[(m * 16 + l15) * 64 + l4 * 8];
    const short8 af1 = *(const short8*)&Web[(m * 16 + l15) * 64 + 32 + l4 * 8];
    acc[m] = __builtin_amdgcn_mfma_f32_16x16x32_bf16(af0, bs0, acc[m], 0, 0, 0);
    acc[m] = __builtin_amdgcn_mfma_f32_16x16x32_bf16(af1, bs1, acc[m], 0, 0, 0);
  }
  const bool ok = (p0 < E);
  #pragma unroll
  for (int m = 0; m < 8; ++m) {
    ushort4 pk;
    pk.x = f2bf(fmaxf(bfbits2f(xr[m].x) + acc[m][0], 0.f));
    pk.y = f2bf(fmaxf(bfbits2f(xr[m].y) + acc[m][1], 0.f));
    pk.z = f2bf(fmaxf(bfbits2f(xr[m].z) + acc[m][2], 0.f));
    pk.w = f2bf(fmaxf(bfbits2f(xr[m].w) + acc[m][3], 0.f));
    if (ok) *(ushort4*)&msg[(size_t)pd * 128 + m * 16 + l4 * 4] = pk;
  }
}

// ---------- aggr: SEQUENTIAL dst-CSR segment-sum ----------
__global__ __launch_bounds__(256) void aggr_kernel(
    const unsigned short* __restrict__ xb, const int* __restrict__ off_d,
    const int* __restrict__ cnt_d, const unsigned int* __restrict__ msg32,
    unsigned int* __restrict__ U, int N) {
  const int idx = blockIdx.x * 256 + threadIdx.x;
  if (idx >= N * 64) return;
  const int n = idx >> 6, d = idx & 63;
  const int o = off_d[n], c = cnt_d[n];
  float a0 = 0.f, a1 = 0.f, b0 = 0.f, b1 = 0.f;
  const unsigned int* p = msg32 + (size_t)o * 64 + d;
  int q = 0;
  for (; q + 4 <= c; q += 4) {
    const unsigned int m0 = p[0], m1 = p[64], m2 = p[128], m3 = p[192];
    a0 += __uint_as_float(m0 << 16) + __uint_as_float(m1 << 16);
    b0 += __uint_as_float(m2 << 16) + __uint_as_float(m3 << 16);
    a1 += __uint_as_float(m0 & 0xffff0000u) + __uint_as_float(m1 & 0xffff0000u);
    b1 += __uint_as_float(m2 & 0xffff0000u) + __uint_as_float(m3 & 0xffff0000u);
    p += 256;
  }
  for (; q < c; ++q) {
    const unsigned int mm = p[0];
    a0 += __uint_as_float(mm << 16);
    a1 += __uint_as_float(mm & 0xffff0000u);
    p += 64;
  }
  const unsigned int xp = ((const unsigned int*)xb)[(size_t)n * 64 + d];
  const float u0 = fmaf(1.00001f, bfbits2f(xp & 0xffffu), a0 + b0);
  const float u1 = fmaf(1.00001f, __uint_as_float(xp & 0xffff0000u), a1 + b1);
  U[(size_t)n * 64 + d] = ((unsigned int)f2bf(u1) << 16) | f2bf(u0);
}

// ---------- streaming MFMA node GEMMs, no LDS ----------
__global__ __launch_bounds__(256) void gemm_kernel(
    const unsigned short* __restrict__ xb, const unsigned short* __restrict__ Ub,
    const unsigned short* __restrict__ Wnb, const unsigned short* __restrict__ Wrb,
    const float* __restrict__ b_nn, float* __restrict__ out, int N) {
  const int lane = threadIdx.x & 63;
  const int l15 = lane & 15, l4 = lane >> 4;
  const int gw = (blockIdx.x * 256 + threadIdx.x) >> 6;
  const int ntiles = (N + 15) >> 4;
  if (gw >= ntiles) return;
  const int n0 = gw * 16 + l15;
  const int n = (n0 < N) ? n0 : (N - 1);
  short8 bu[4], bx[4];
  #pragma unroll
  for (int s = 0; s < 4; ++s) {
    bu[s] = *(const short8*)&Ub[(size_t)n * 128 + s * 32 + l4 * 8];
    bx[s] = *(const short8*)&xb[(size_t)n * 128 + s * 32 + l4 * 8];
  }
  const bool ok = (n0 < N);
  #pragma unroll
  for (int m = 0; m < 8; ++m) {
    f32x4 an = (f32x4){0.f, 0.f, 0.f, 0.f};
    f32x4 ar = (f32x4){0.f, 0.f, 0.f, 0.f};
    #pragma unroll
    for (int s = 0; s < 4; ++s) {
      const short8 wn = *(const short8*)&Wnb[(m * 16 + l15) * 128 + s * 32 + l4 * 8];
      const short8 wr = *(const short8*)&Wrb[(m * 16 + l15) * 128 + s * 32 + l4 * 8];
      an = __builtin_amdgcn_mfma_f32_16x16x32_bf16(wn, bu[s], an, 0, 0, 0);
      ar = __builtin_amdgcn_mfma_f32_16x16x32_bf16(wr, bx[s], ar, 0, 0, 0);
    }
    const float4 bb = *(const float4*)&b_nn[m * 16 + l4 * 4];
    float4 o4;
    o4.x = (fmaxf(an[0] + bb.x, 0.f) + ar[0]) * INV_SQRT2;
    o4.y = (fmaxf(an[1] + bb.y, 0.f) + ar[1]) * INV_SQRT2;
    o4.z = (fmaxf(an[2] + bb.z, 0.f) + ar[2]) * INV_SQRT2;
    o4.w = (fmaxf(an[3] + bb.w, 0.f) + ar[3]) * INV_SQRT2;
    if (ok) *(float4*)&out[(size_t)n0 * 128 + m * 16 + l4 * 4] = o4;
  }
}

// ---------- legacy fallback (round-1 path, atomics) ----------
__global__ __launch_bounds__(256) void edge_kernel_legacy(
    const float* __restrict__ x, const int* __restrict__ ei,
    const float* __restrict__ edge_attr, const float* __restrict__ W_edge,
    float* aggr, int E) {
  __shared__ float Wl[64 * 128];
  __shared__ float Al[32 * 64];
  const int tid = threadIdx.x;
  for (int idx = tid; idx < 128 * 64; idx += 256) {
    int o = idx >> 6, k = idx & 63;
    Wl[k * 128 + o] = W_edge[idx];
  }
  const int og = tid & 31;
  const int er = tid >> 5;
  const int ntiles = (E + 31) >> 5;
  for (int tile = blockIdx.x; tile < ntiles; tile += gridDim.x) {
    __syncthreads();
    {
      const float* src_ptr = edge_attr + (size_t)tile * 32 * 64;
      const int limit = E * 64 - tile * 32 * 64;
      for (int idx = tid; idx < 2048; idx += 256)
        Al[idx] = (idx < limit) ? src_ptr[idx] : 0.f;
    }
    __syncthreads();
    float acc[4][4] = {};
    #pragma unroll 4
    for (int k = 0; k < 64; ++k) {
      const float4 w = *(const float4*)&Wl[k * 128 + og * 4];
      #pragma unroll
      for (int j = 0; j < 4; ++j) {
        const float a = Al[(er * 4 + j) * 64 + k];
        acc[j][0] = fmaf(a, w.x, acc[j][0]);
        acc[j][1] = fmaf(a, w.y, acc[j][1]);
        acc[j][2] = fmaf(a, w.z, acc[j][2]);
        acc[j][3] = fmaf(a, w.w, acc[j][3]);
      }
    }
    #pragma unroll
    for (int j = 0; j < 4; ++j) {
      const int e = tile * 32 + er * 4 + j;
      if (e < E) {
        const int s = ei[e];
        const int d = ei[E + e];
        const float4 xv = *(const float4*)&x[(size_t)s * 128 + og * 4];
        float* ap = aggr + (size_t)d * 128 + og * 4;
        atomicAdd(ap + 0, fmaxf(xv.x + acc[j][0], 0.f));
        atomicAdd(ap + 1, fmaxf(xv.y + acc[j][1], 0.f));
        atomicAdd(ap + 2, fmaxf(xv.z + acc[j][2], 0.f));
        atomicAdd(ap + 3, fmaxf(xv.w + acc[j][3], 0.f));
      }
    }
  }
}

__global__ __launch_bounds__(256) void node_kernel_legacy(
    const float* __restrict__ x, const float* __restrict__ WT,
    const float* __restrict__ b_nn, float* io, int N) {
  __shared__ float Ul[16 * 128];
  __shared__ float Xl[16 * 128];
  const int tid = threadIdx.x;
  const int og = tid & 31;
  const int nr = tid >> 5;
  const float* WnnT = WT;
  const float* WresT = WT + 128 * 128;
  const int ntiles = (N + 15) >> 4;
  for (int tile = blockIdx.x; tile < ntiles; tile += gridDim.x) {
    __syncthreads();
    {
      const size_t base = (size_t)tile * 16 * 128;
      const int limit = N * 128 - (int)base;
      for (int idx = tid; idx < 2048; idx += 256) {
        const float xv = (idx < limit) ? x[base + idx] : 0.f;
        const float av = (idx < limit) ? io[base + idx] : 0.f;
        Xl[idx] = xv;
        Ul[idx] = fmaf(1.00001f, xv, av);
      }
    }
    __syncthreads();
    float accn[2][4] = {}, accr[2][4] = {};
    #pragma unroll 4
    for (int kk = 0; kk < 128; ++kk) {
      const float4 wn = *(const float4*)&WnnT[kk * 128 + og * 4];
      const float4 wr = *(const float4*)&WresT[kk * 128 + og * 4];
      #pragma unroll
      for (int j = 0; j < 2; ++j) {
        const float u = Ul[(nr * 2 + j) * 128 + kk];
        const float xx = Xl[(nr * 2 + j) * 128 + kk];
        accn[j][0] = fmaf(u, wn.x, accn[j][0]);
        accn[j][1] = fmaf(u, wn.y, accn[j][1]);
        accn[j][2] = fmaf(u, wn.z, accn[j][2]);
        accn[j][3] = fmaf(u, wn.w, accn[j][3]);
        accr[j][0] = fmaf(xx, wr.x, accr[j][0]);
        accr[j][1] = fmaf(xx, wr.y, accr[j][1]);
        accr[j][2] = fmaf(xx, wr.z, accr[j][2]);
        accr[j][3] = fmaf(xx, wr.w, accr[j][3]);
      }
    }
    const float4 b = *(const float4*)&b_nn[og * 4];
    #pragma unroll
    for (int j = 0; j < 2; ++j) {
      const int n = tile * 16 + nr * 2 + j;
      if (n < N) {
        float4 o4;
        o4.x = (fmaxf(accn[j][0] + b.x, 0.f) + accr[j][0]) * INV_SQRT2;
        o4.y = (fmaxf(accn[j][1] + b.y, 0.f) + accr[j][1]) * INV_SQRT2;
        o4.z = (fmaxf(accn[j][2] + b.z, 0.f) + accr[j][2]) * INV_SQRT2;
        o4.w = (fmaxf(accn[j][3] + b.w, 0.f) + accr[j][3]) * INV_SQRT2;
        *(float4*)&io[(size_t)n * 128 + og * 4] = o4;
      }
    }
  }
}

extern "C" void kernel_launch(void* const* d_in, const int* in_sizes, int n_in,
                              void* d_out, int out_size, void* d_ws, size_t ws_size,
                              hipStream_t stream) {
  const float* x      = (const float*)d_in[0];
  const int*   ei     = (const int*)d_in[1];
  const float* ea     = (const float*)d_in[2];
  const float* W_edge = (const float*)d_in[3];
  const float* W_nn   = (const float*)d_in[4];
  const float* b_nn   = (const float*)d_in[5];
  const float* W_res  = (const float*)d_in[6];
  float* out = (float*)d_out;
  const int N = in_sizes[0] / 128;
  const int E = in_sizes[2] / 64;
  const int NX = N * 128;

  char* ws = (char*)d_ws;
  const size_t WT_OFF    = 0;                                  // 131072 B
  const size_t WEB_OFF   = 131072;
  const size_t WNB_OFF   = WEB_OFF + 16384;
  const size_t WRB_OFF   = WNB_OFF + 32768;
  const size_t CNT_OFF   = WRB_OFF + 32768;                    // 2N ints
  const size_t OFF_OFF   = CNT_OFF + (size_t)N * 8;            // 2N ints
  const size_t CUR_OFF   = OFF_OFF + (size_t)N * 8;            // 2N ints
  const size_t BSUM_OFF  = CUR_OFF + (size_t)N * 8;            // 2048 B
  const size_t SD_OFF    = (BSUM_OFF + 2048 + 255) & ~(size_t)255;   // E uint2
  const size_t XB_OFF    = (SD_OFF + (size_t)E * 8 + 255) & ~(size_t)255;
  const size_t ATTRS_OFF = (XB_OFF + (size_t)NX * 2 + 255) & ~(size_t)255;  // E*64 bf16
  const size_t MSG_OFF   = (ATTRS_OFF + (size_t)E * 128 + 255) & ~(size_t)255;
  const size_t NEED      = MSG_OFF + (size_t)E * 256;
  // U (N*64 dwords = NX*2 bytes) overlays attr_s (dead after msg; attr_s >= U)

  float* WT = (float*)(ws + WT_OFF);
  unsigned short* Web = (unsigned short*)(ws + WEB_OFF);
  unsigned short* Wnb = (unsigned short*)(ws + WNB_OFF);
  unsigned short* Wrb = (unsigned short*)(ws + WRB_OFF);
  unsigned short* xb  = (unsigned short*)(ws + XB_OFF);

  if (ws_size >= NEED) {
    prep_kernel<<<(NX + 255) / 256, 256, 0, stream>>>(
        x, W_edge, W_nn, W_res, WT, Web, Wnb, Wrb, xb, NX);

    int* cnt  = (int*)(ws + CNT_OFF);
    int* off  = (int*)(ws + OFF_OFF);
    int* cur  = (int*)(ws + CUR_OFF);
    int* bsum = (int*)(ws + BSUM_OFF);
    uint2* sd_s = (uint2*)(ws + SD_OFF);
    unsigned short* attr_s = (unsigned short*)(ws + ATTRS_OFF);
    unsigned short* msg = (unsigned short*)(ws + MSG_OFF);
    unsigned int* U = (unsigned int*)(ws + ATTRS_OFF);   // overlay

    const int nb = (N + 255) / 256;   // <= 512 per scan chain
    hipMemsetAsync(cnt, 0, (size_t)N * 8, stream);
    hist2_kernel<<<(E + 255) / 256, 256, 0, stream>>>(ei, cnt, E, N);
    // src scan chain
    scan1_kernel<<<nb, 256, 0, stream>>>(cnt, off, bsum, N);
    scan2_kernel<<<1, 512, 0, stream>>>(bsum, nb);
    scan3_kernel<<<nb, 256, 0, stream>>>(off, cur, bsum, N);
    // dst scan chain
    scan1_kernel<<<nb, 256, 0, stream>>>(cnt + N, off + N, bsum, N);
    scan2_kernel<<<1, 512, 0, stream>>>(bsum, nb);
    scan3_kernel<<<nb, 256, 0, stream>>>(off + N, cur + N, bsum, N);

    bscatter_kernel<<<(E + 63) / 64, 256, 0, stream>>>(
        ei, cur, ea, attr_s, sd_s, E, N);

    const int etiles = (E + 15) / 16;
    msg_mfma_kernel<<<(etiles + 3) / 4, 256, 0, stream>>>(
        xb, sd_s, attr_s, Web, msg, E);

    aggr_kernel<<<(N * 64 + 255) / 256, 256, 0, stream>>>(
        xb, off + N, cnt + N, (const unsigned int*)msg, U, N);

    const int ntilesn = (N + 15) / 16;
    gemm_kernel<<<(ntilesn + 3) / 4, 256, 0, stream>>>(
        xb, (const unsigned short*)U, Wnb, Wrb, b_nn, out, N);
  } else {
    prep_kernel<<<64, 256, 0, stream>>>(
        x, W_edge, W_nn, W_res, WT, Web, Wnb, Wrb, (unsigned short*)(ws + WEB_OFF), 0);
    hipMemsetAsync(d_out, 0, (size_t)N * 128 * sizeof(float), stream);
    const int etiles = (E + 31) / 32;
    edge_kernel_legacy<<<(etiles < 4096 ? etiles : 4096), 256, 0, stream>>>(
        x, ei, ea, W_edge, out, E);
    const int ntiles = (N + 15) / 16;
    node_kernel_legacy<<<(ntiles < 2048 ? ntiles : 2048), 256, 0, stream>>>(
        x, WT, b_nn, out, N);
  }
}

// Round 10
// 316.652 us; speedup vs baseline: 1.0833x; 1.0833x over previous
//
#include <hip/hip_runtime.h>
#include <hip/hip_bf16.h>

#define INV_SQRT2 0.7071067811865475f

typedef __attribute__((ext_vector_type(8))) short short8;
typedef __attribute__((ext_vector_type(4))) float f32x4;

static __device__ __forceinline__ unsigned short f2bf(float f) {
  __hip_bfloat16 h = __float2bfloat16(f);
  return *(unsigned short*)&h;
}
static __device__ __forceinline__ float bfbits2f(unsigned int u16) {
  return __uint_as_float(u16 << 16);
}

// ---------- prep: bf16 weight copies (+ legacy f32 k-major WT) ----------
__global__ __launch_bounds__(256) void prep_kernel(
    const float* __restrict__ W_edge, const float* __restrict__ W_nn,
    const float* __restrict__ W_res, float* __restrict__ WT,
    unsigned short* __restrict__ Web, unsigned short* __restrict__ Wnb,
    unsigned short* __restrict__ Wrb) {
  int idx = blockIdx.x * 256 + threadIdx.x;
  if (idx < 8192) Web[idx] = f2bf(W_edge[idx]);
  if (idx < 16384) {
    Wnb[idx] = f2bf(W_nn[idx]);
    Wrb[idx] = f2bf(W_res[idx]);
    int o = idx >> 7, k = idx & 127;
    WT[k * 128 + o] = W_nn[idx];
    WT[16384 + k * 128 + o] = W_res[idx];
  }
}

// ---------- CSR build (dst) ----------
__global__ __launch_bounds__(256) void hist_kernel(const int* __restrict__ ei,
                                                   int* cnt, int E) {
  int e = blockIdx.x * 256 + threadIdx.x;
  if (e < E) atomicAdd(&cnt[ei[E + e]], 1);
}

__global__ __launch_bounds__(256) void scan1_kernel(const int* __restrict__ cnt,
                                                    int* off, int* bsum, int N) {
  __shared__ int s[256];
  const int tid = threadIdx.x;
  const int gid = blockIdx.x * 256 + tid;
  const int v = (gid < N) ? cnt[gid] : 0;
  s[tid] = v;
  for (int o = 1; o < 256; o <<= 1) {
    __syncthreads();
    int t = (tid >= o) ? s[tid - o] : 0;
    __syncthreads();
    s[tid] += t;
  }
  if (gid < N) off[gid] = s[tid] - v;
  if (tid == 255) bsum[blockIdx.x] = s[255];
}

__global__ __launch_bounds__(512) void scan2_kernel(int* bsum, int nb) {
  __shared__ int s[512];
  const int tid = threadIdx.x;
  const int v = (tid < nb) ? bsum[tid] : 0;
  s[tid] = v;
  for (int o = 1; o < 512; o <<= 1) {
    __syncthreads();
    int t = (tid >= o) ? s[tid - o] : 0;
    __syncthreads();
    s[tid] += t;
  }
  if (tid < nb) bsum[tid] = s[tid] - v;
}

__global__ __launch_bounds__(256) void scan3_kernel(int* off, int* cur,
                                                    const int* __restrict__ bsum,
                                                    int N) {
  int gid = blockIdx.x * 256 + threadIdx.x;
  if (gid < N) {
    int v = off[gid] + bsum[blockIdx.x];
    off[gid] = v;
    cur[gid] = v;
  }
}

__global__ __launch_bounds__(256) void rank_kernel(const int* __restrict__ ei,
                                                   int* cur, int* rank, int E) {
  int e = blockIdx.x * 256 + threadIdx.x;
  if (e < E) rank[e] = atomicAdd(&cur[ei[E + e]], 1);
}

// ---------- msg: seq attr/f32-x-gather MFMA -> bf16 row at rank slot ----------
__global__ __launch_bounds__(256) void msg_mfma_kernel(
    const float* __restrict__ x, const int* __restrict__ ei,
    const int* __restrict__ rank, const float* __restrict__ attr,
    const unsigned short* __restrict__ Web,
    unsigned short* __restrict__ msg, int E) {
  const int lane = threadIdx.x & 63;
  const int l15 = lane & 15;
  const int l4 = lane >> 4;
  const int t = (blockIdx.x * 256 + threadIdx.x) >> 6;   // one 16-edge tile per wave
  const int ntiles = (E + 15) >> 4;
  if (t >= ntiles) return;
  const int e0 = t * 16 + l15;
  const int e = (e0 < E) ? e0 : (E - 1);
  const int sidx = ei[e];
  const int p = rank[e];
  // hoisted x-row gather (f32), independent of MFMA chain
  float4 xr[8];
  #pragma unroll
  for (int m = 0; m < 8; ++m)
    xr[m] = *(const float4*)&x[(size_t)sidx * 128 + m * 16 + l4 * 4];
  // attr row (f32) -> bf16 B-frags
  float4 q[4];
  #pragma unroll
  for (int s = 0; s < 2; ++s) {
    q[s * 2 + 0] = *(const float4*)&attr[(size_t)e * 64 + s * 32 + l4 * 8];
    q[s * 2 + 1] = *(const float4*)&attr[(size_t)e * 64 + s * 32 + l4 * 8 + 4];
  }
  f32x4 acc[8];
  #pragma unroll
  for (int m = 0; m < 8; ++m) acc[m] = (f32x4){0.f, 0.f, 0.f, 0.f};
  #pragma unroll
  for (int s = 0; s < 2; ++s) {
    short8 bt;
    bt[0] = (short)f2bf(q[s * 2].x); bt[1] = (short)f2bf(q[s * 2].y);
    bt[2] = (short)f2bf(q[s * 2].z); bt[3] = (short)f2bf(q[s * 2].w);
    bt[4] = (short)f2bf(q[s * 2 + 1].x); bt[5] = (short)f2bf(q[s * 2 + 1].y);
    bt[6] = (short)f2bf(q[s * 2 + 1].z); bt[7] = (short)f2bf(q[s * 2 + 1].w);
    #pragma unroll
    for (int m = 0; m < 8; ++m) {
      const short8 af = *(const short8*)&Web[(m * 16 + l15) * 64 + s * 32 + l4 * 8];
      acc[m] = __builtin_amdgcn_mfma_f32_16x16x32_bf16(af, bt, acc[m], 0, 0, 0);
    }
  }
  const bool ok = (e0 < E);
  #pragma unroll
  for (int m = 0; m < 8; ++m) {
    ushort4 pk;
    pk.x = f2bf(fmaxf(xr[m].x + acc[m][0], 0.f));
    pk.y = f2bf(fmaxf(xr[m].y + acc[m][1], 0.f));
    pk.z = f2bf(fmaxf(xr[m].z + acc[m][2], 0.f));
    pk.w = f2bf(fmaxf(xr[m].w + acc[m][3], 0.f));
    if (ok) *(ushort4*)&msg[(size_t)p * 128 + m * 16 + l4 * 4] = pk;
  }
}

// ---------- fused node: seq CSR slab segment-sum + both MFMAs + out ----------
// One wave per 16 nodes. Wave-private LDS U tile (bf16x2 packed, XOR-swizzled).
__global__ __launch_bounds__(256) void node_fused_kernel(
    const float* __restrict__ x, const int* __restrict__ off,
    const int* __restrict__ cnt, const unsigned int* __restrict__ msg32,
    const unsigned short* __restrict__ Wnb, const unsigned short* __restrict__ Wrb,
    const float* __restrict__ b_nn, float* __restrict__ out, int N) {
  __shared__ __align__(16) unsigned int Ul[4][16 * 64];
  const int tid = threadIdx.x;
  const int w = tid >> 6, lane = tid & 63;
  const int l15 = lane & 15, l4 = lane >> 4;
  const int t = (blockIdx.x * 256 + tid) >> 6;
  const int ntiles = (N + 15) >> 4;
  if (t >= ntiles) return;
  const int n0 = t * 16;
  unsigned int* U = Ul[w];
  // phase A: per-node contiguous-slab segment-sum; lane = dword channel-pair
  for (int j = 0; j < 16; ++j) {
    const int n = n0 + j;
    unsigned int pk = 0;
    if (n < N) {
      const int o = off[n];
      const int c = cnt[n];
      const unsigned int* p = msg32 + (size_t)o * 64 + lane;
      float a0 = 0.f, a1 = 0.f, b0 = 0.f, b1 = 0.f;
      int q = 0;
      for (; q + 4 <= c; q += 4) {
        const unsigned int m0 = p[0], m1 = p[64], m2 = p[128], m3 = p[192];
        a0 += __uint_as_float(m0 << 16) + __uint_as_float(m1 << 16);
        b0 += __uint_as_float(m2 << 16) + __uint_as_float(m3 << 16);
        a1 += __uint_as_float(m0 & 0xffff0000u) + __uint_as_float(m1 & 0xffff0000u);
        b1 += __uint_as_float(m2 & 0xffff0000u) + __uint_as_float(m3 & 0xffff0000u);
        p += 256;
      }
      for (; q < c; ++q) {
        const unsigned int mm = p[0];
        a0 += __uint_as_float(mm << 16);
        a1 += __uint_as_float(mm & 0xffff0000u);
        p += 64;
      }
      const float2 xv = *(const float2*)&x[(size_t)n * 128 + lane * 2];
      const float u0 = fmaf(1.00001f, xv.x, a0 + b0);
      const float u1 = fmaf(1.00001f, xv.y, a1 + b1);
      pk = ((unsigned int)f2bf(u1) << 16) | f2bf(u0);
    }
    U[j * 64 + (lane ^ ((j & 7) << 2))] = pk;   // swizzled, conflict-free
  }
  // phase B: B-frags from wave-private LDS (+ x re-read as bf16), MFMAs
  const int nn = n0 + l15;
  const int nld = (nn < N) ? nn : (N - 1);
  short8 bu[4], bx[4];
  #pragma unroll
  for (int s = 0; s < 4; ++s) {
    const int dw = (s * 16 + l4 * 4) ^ ((l15 & 7) << 2);
    bu[s] = *(const short8*)&U[l15 * 64 + dw];
    const float4 q0 = *(const float4*)&x[(size_t)nld * 128 + s * 32 + l4 * 8];
    const float4 q1 = *(const float4*)&x[(size_t)nld * 128 + s * 32 + l4 * 8 + 4];
    short8 bt;
    bt[0] = (short)f2bf(q0.x); bt[1] = (short)f2bf(q0.y);
    bt[2] = (short)f2bf(q0.z); bt[3] = (short)f2bf(q0.w);
    bt[4] = (short)f2bf(q1.x); bt[5] = (short)f2bf(q1.y);
    bt[6] = (short)f2bf(q1.z); bt[7] = (short)f2bf(q1.w);
    bx[s] = bt;
  }
  const bool ok = (nn < N);
  #pragma unroll
  for (int m = 0; m < 8; ++m) {
    f32x4 an = (f32x4){0.f, 0.f, 0.f, 0.f};
    f32x4 ar = (f32x4){0.f, 0.f, 0.f, 0.f};
    #pragma unroll
    for (int s = 0; s < 4; ++s) {
      const short8 wn = *(const short8*)&Wnb[(m * 16 + l15) * 128 + s * 32 + l4 * 8];
      const short8 wr = *(const short8*)&Wrb[(m * 16 + l15) * 128 + s * 32 + l4 * 8];
      an = __builtin_amdgcn_mfma_f32_16x16x32_bf16(wn, bu[s], an, 0, 0, 0);
      ar = __builtin_amdgcn_mfma_f32_16x16x32_bf16(wr, bx[s], ar, 0, 0, 0);
    }
    const float4 bb = *(const float4*)&b_nn[m * 16 + l4 * 4];
    float4 o4;
    o4.x = (fmaxf(an[0] + bb.x, 0.f) + ar[0]) * INV_SQRT2;
    o4.y = (fmaxf(an[1] + bb.y, 0.f) + ar[1]) * INV_SQRT2;
    o4.z = (fmaxf(an[2] + bb.z, 0.f) + ar[2]) * INV_SQRT2;
    o4.w = (fmaxf(an[3] + bb.w, 0.f) + ar[3]) * INV_SQRT2;
    if (ok) *(float4*)&out[(size_t)nn * 128 + m * 16 + l4 * 4] = o4;
  }
}

// ---------- legacy fallback (round-1 path, atomics) ----------
__global__ __launch_bounds__(256) void edge_kernel_legacy(
    const float* __restrict__ x, const int* __restrict__ ei,
    const float* __restrict__ edge_attr, const float* __restrict__ W_edge,
    float* aggr, int E) {
  __shared__ float Wl[64 * 128];
  __shared__ float Al[32 * 64];
  const int tid = threadIdx.x;
  for (int idx = tid; idx < 128 * 64; idx += 256) {
    int o = idx >> 6, k = idx & 63;
    Wl[k * 128 + o] = W_edge[idx];
  }
  const int og = tid & 31;
  const int er = tid >> 5;
  const int ntiles = (E + 31) >> 5;
  for (int tile = blockIdx.x; tile < ntiles; tile += gridDim.x) {
    __syncthreads();
    {
      const float* src_ptr = edge_attr + (size_t)tile * 32 * 64;
      const int limit = E * 64 - tile * 32 * 64;
      for (int idx = tid; idx < 2048; idx += 256)
        Al[idx] = (idx < limit) ? src_ptr[idx] : 0.f;
    }
    __syncthreads();
    float acc[4][4] = {};
    #pragma unroll 4
    for (int k = 0; k < 64; ++k) {
      const float4 w = *(const float4*)&Wl[k * 128 + og * 4];
      #pragma unroll
      for (int j = 0; j < 4; ++j) {
        const float a = Al[(er * 4 + j) * 64 + k];
        acc[j][0] = fmaf(a, w.x, acc[j][0]);
        acc[j][1] = fmaf(a, w.y, acc[j][1]);
        acc[j][2] = fmaf(a, w.z, acc[j][2]);
        acc[j][3] = fmaf(a, w.w, acc[j][3]);
      }
    }
    #pragma unroll
    for (int j = 0; j < 4; ++j) {
      const int e = tile * 32 + er * 4 + j;
      if (e < E) {
        const int s = ei[e];
        const int d = ei[E + e];
        const float4 xv = *(const float4*)&x[(size_t)s * 128 + og * 4];
        float* ap = aggr + (size_t)d * 128 + og * 4;
        atomicAdd(ap + 0, fmaxf(xv.x + acc[j][0], 0.f));
        atomicAdd(ap + 1, fmaxf(xv.y + acc[j][1], 0.f));
        atomicAdd(ap + 2, fmaxf(xv.z + acc[j][2], 0.f));
        atomicAdd(ap + 3, fmaxf(xv.w + acc[j][3], 0.f));
      }
    }
  }
}

__global__ __launch_bounds__(256) void node_kernel_legacy(
    const float* __restrict__ x, const float* __restrict__ WT,
    const float* __restrict__ b_nn, float* io, int N) {
  __shared__ float Ul[16 * 128];
  __shared__ float Xl[16 * 128];
  const int tid = threadIdx.x;
  const int og = tid & 31;
  const int nr = tid >> 5;
  const float* WnnT = WT;
  const float* WresT = WT + 128 * 128;
  const int ntiles = (N + 15) >> 4;
  for (int tile = blockIdx.x; tile < ntiles; tile += gridDim.x) {
    __syncthreads();
    {
      const size_t base = (size_t)tile * 16 * 128;
      const int limit = N * 128 - (int)base;
      for (int idx = tid; idx < 2048; idx += 256) {
        const float xv = (idx < limit) ? x[base + idx] : 0.f;
        const float av = (idx < limit) ? io[base + idx] : 0.f;
        Xl[idx] = xv;
        Ul[idx] = fmaf(1.00001f, xv, av);
      }
    }
    __syncthreads();
    float accn[2][4] = {}, accr[2][4] = {};
    #pragma unroll 4
    for (int kk = 0; kk < 128; ++kk) {
      const float4 wn = *(const float4*)&WnnT[kk * 128 + og * 4];
      const float4 wr = *(const float4*)&WresT[kk * 128 + og * 4];
      #pragma unroll
      for (int j = 0; j < 2; ++j) {
        const float u = Ul[(nr * 2 + j) * 128 + kk];
        const float xx = Xl[(nr * 2 + j) * 128 + kk];
        accn[j][0] = fmaf(u, wn.x, accn[j][0]);
        accn[j][1] = fmaf(u, wn.y, accn[j][1]);
        accn[j][2] = fmaf(u, wn.z, accn[j][2]);
        accn[j][3] = fmaf(u, wn.w, accn[j][3]);
        accr[j][0] = fmaf(xx, wr.x, accr[j][0]);
        accr[j][1] = fmaf(xx, wr.y, accr[j][1]);
        accr[j][2] = fmaf(xx, wr.z, accr[j][2]);
        accr[j][3] = fmaf(xx, wr.w, accr[j][3]);
      }
    }
    const float4 b = *(const float4*)&b_nn[og * 4];
    #pragma unroll
    for (int j = 0; j < 2; ++j) {
      const int n = tile * 16 + nr * 2 + j;
      if (n < N) {
        float4 o4;
        o4.x = (fmaxf(accn[j][0] + b.x, 0.f) + accr[j][0]) * INV_SQRT2;
        o4.y = (fmaxf(accn[j][1] + b.y, 0.f) + accr[j][1]) * INV_SQRT2;
        o4.z = (fmaxf(accn[j][2] + b.z, 0.f) + accr[j][2]) * INV_SQRT2;
        o4.w = (fmaxf(accn[j][3] + b.w, 0.f) + accr[j][3]) * INV_SQRT2;
        *(float4*)&io[(size_t)n * 128 + og * 4] = o4;
      }
    }
  }
}

extern "C" void kernel_launch(void* const* d_in, const int* in_sizes, int n_in,
                              void* d_out, int out_size, void* d_ws, size_t ws_size,
                              hipStream_t stream) {
  const float* x      = (const float*)d_in[0];
  const int*   ei     = (const int*)d_in[1];
  const float* ea     = (const float*)d_in[2];
  const float* W_edge = (const float*)d_in[3];
  const float* W_nn   = (const float*)d_in[4];
  const float* b_nn   = (const float*)d_in[5];
  const float* W_res  = (const float*)d_in[6];
  float* out = (float*)d_out;
  const int N = in_sizes[0] / 128;
  const int E = in_sizes[2] / 64;

  char* ws = (char*)d_ws;
  const size_t WT_OFF    = 0;                                  // 131072 B
  const size_t WEB_OFF   = 131072;
  const size_t WNB_OFF   = WEB_OFF + 16384;
  const size_t WRB_OFF   = WNB_OFF + 32768;
  const size_t CNT_OFF   = WRB_OFF + 32768;                    // N ints
  const size_t OFF_OFF   = CNT_OFF + (size_t)N * 4;
  const size_t CUR_OFF   = OFF_OFF + (size_t)N * 4;
  const size_t BSUM_OFF  = CUR_OFF + (size_t)N * 4;
  const size_t RANK_OFF  = (BSUM_OFF + 2048 + 255) & ~(size_t)255;   // E ints
  const size_t MSG_OFF   = (RANK_OFF + (size_t)E * 4 + 255) & ~(size_t)255;
  const size_t NEED      = MSG_OFF + (size_t)E * 256;

  float* WT = (float*)(ws + WT_OFF);
  unsigned short* Web = (unsigned short*)(ws + WEB_OFF);
  unsigned short* Wnb = (unsigned short*)(ws + WNB_OFF);
  unsigned short* Wrb = (unsigned short*)(ws + WRB_OFF);
  prep_kernel<<<64, 256, 0, stream>>>(W_edge, W_nn, W_res, WT, Web, Wnb, Wrb);

  if (ws_size >= NEED) {
    int* cnt  = (int*)(ws + CNT_OFF);
    int* off  = (int*)(ws + OFF_OFF);
    int* cur  = (int*)(ws + CUR_OFF);
    int* bsum = (int*)(ws + BSUM_OFF);
    int* rank = (int*)(ws + RANK_OFF);
    unsigned short* msg = (unsigned short*)(ws + MSG_OFF);

    const int nb = (N + 255) / 256;   // <= 512
    hipMemsetAsync(cnt, 0, (size_t)N * 4, stream);
    hist_kernel<<<(E + 255) / 256, 256, 0, stream>>>(ei, cnt, E);
    scan1_kernel<<<nb, 256, 0, stream>>>(cnt, off, bsum, N);
    scan2_kernel<<<1, 512, 0, stream>>>(bsum, nb);
    scan3_kernel<<<nb, 256, 0, stream>>>(off, cur, bsum, N);
    rank_kernel<<<(E + 255) / 256, 256, 0, stream>>>(ei, cur, rank, E);

    const int etiles = (E + 15) / 16;
    msg_mfma_kernel<<<(etiles + 3) / 4, 256, 0, stream>>>(
        x, ei, rank, ea, Web, msg, E);

    const int ntilesn = (N + 15) / 16;
    node_fused_kernel<<<(ntilesn + 3) / 4, 256, 0, stream>>>(
        x, off, cnt, (const unsigned int*)msg, Wnb, Wrb, b_nn, out, N);
  } else {
    hipMemsetAsync(d_out, 0, (size_t)N * 128 * sizeof(float), stream);
    const int etiles = (E + 31) / 32;
    edge_kernel_legacy<<<(etiles < 4096 ? etiles : 4096), 256, 0, stream>>>(
        x, ei, ea, W_edge, out, E);
    const int ntiles = (N + 15) / 16;
    node_kernel_legacy<<<(ntiles < 2048 ? ntiles : 2048), 256, 0, stream>>>(
        x, WT, b_nn, out, N);
  }
}

// Round 11
// 281.118 us; speedup vs baseline: 1.2202x; 1.1264x over previous
//
#include <hip/hip_runtime.h>
#include <hip/hip_bf16.h>

#define INV_SQRT2 0.7071067811865475f

typedef __attribute__((ext_vector_type(8))) short short8;
typedef __attribute__((ext_vector_type(4))) float f32x4;

static __device__ __forceinline__ unsigned short f2bf(float f) {
  __hip_bfloat16 h = __float2bfloat16(f);
  return *(unsigned short*)&h;
}
static __device__ __forceinline__ float bfbits2f(unsigned int u16) {
  return __uint_as_float(u16 << 16);
}

// ---------- prep: bf16 weight copies (+ legacy f32 k-major WT) ----------
__global__ __launch_bounds__(256) void prep_kernel(
    const float* __restrict__ W_edge, const float* __restrict__ W_nn,
    const float* __restrict__ W_res, float* __restrict__ WT,
    unsigned short* __restrict__ Web, unsigned short* __restrict__ Wnb,
    unsigned short* __restrict__ Wrb) {
  int idx = blockIdx.x * 256 + threadIdx.x;
  if (idx < 8192) Web[idx] = f2bf(W_edge[idx]);
  if (idx < 16384) {
    Wnb[idx] = f2bf(W_nn[idx]);
    Wrb[idx] = f2bf(W_res[idx]);
    int o = idx >> 7, k = idx & 127;
    WT[k * 128 + o] = W_nn[idx];
    WT[16384 + k * 128 + o] = W_res[idx];
  }
}

// ---------- CSR build (dst) ----------
__global__ __launch_bounds__(256) void hist_kernel(const int* __restrict__ ei,
                                                   int* cnt, int E) {
  int e = blockIdx.x * 256 + threadIdx.x;
  if (e < E) atomicAdd(&cnt[ei[E + e]], 1);
}

__global__ __launch_bounds__(256) void scan1_kernel(const int* __restrict__ cnt,
                                                    int* off, int* bsum, int N) {
  __shared__ int s[256];
  const int tid = threadIdx.x;
  const int gid = blockIdx.x * 256 + tid;
  const int v = (gid < N) ? cnt[gid] : 0;
  s[tid] = v;
  for (int o = 1; o < 256; o <<= 1) {
    __syncthreads();
    int t = (tid >= o) ? s[tid - o] : 0;
    __syncthreads();
    s[tid] += t;
  }
  if (gid < N) off[gid] = s[tid] - v;
  if (tid == 255) bsum[blockIdx.x] = s[255];
}

__global__ __launch_bounds__(512) void scan2_kernel(int* bsum, int nb) {
  __shared__ int s[512];
  const int tid = threadIdx.x;
  const int v = (tid < nb) ? bsum[tid] : 0;
  s[tid] = v;
  for (int o = 1; o < 512; o <<= 1) {
    __syncthreads();
    int t = (tid >= o) ? s[tid - o] : 0;
    __syncthreads();
    s[tid] += t;
  }
  if (tid < nb) bsum[tid] = s[tid] - v;
}

__global__ __launch_bounds__(256) void scan3_kernel(int* off, int* cur,
                                                    const int* __restrict__ bsum,
                                                    int N) {
  int gid = blockIdx.x * 256 + threadIdx.x;
  if (gid < N) {
    int v = off[gid] + bsum[blockIdx.x];
    off[gid] = v;
    cur[gid] = v;
  }
}

// ---------- msg: seq attr + random x gather, MFMA, slot claimed inline ----------
__global__ __launch_bounds__(256) void msg_mfma_kernel(
    const float* __restrict__ x, const int* __restrict__ ei,
    int* __restrict__ cur, const float* __restrict__ attr,
    const unsigned short* __restrict__ Web,
    unsigned short* __restrict__ msg, int E) {
  const int lane = threadIdx.x & 63;
  const int l15 = lane & 15;
  const int l4 = lane >> 4;
  const int t = (blockIdx.x * 256 + threadIdx.x) >> 6;   // one 16-edge tile per wave
  const int ntiles = (E + 15) >> 4;
  if (t >= ntiles) return;
  const int e0 = t * 16 + l15;
  const int e = (e0 < E) ? e0 : (E - 1);
  const int sidx = ei[e];
  // claim CSR slot inline (order within a node is irrelevant for the sum)
  int p = 0;
  if (l4 == 0 && e0 < E) p = atomicAdd(&cur[ei[E + e]], 1);
  p = __shfl(p, l15);
  // hoisted x-row gather (f32), independent of MFMA chain
  float4 xr[8];
  #pragma unroll
  for (int m = 0; m < 8; ++m)
    xr[m] = *(const float4*)&x[(size_t)sidx * 128 + m * 16 + l4 * 4];
  // attr row (f32) -> bf16 B-frags
  float4 q[4];
  #pragma unroll
  for (int s = 0; s < 2; ++s) {
    q[s * 2 + 0] = *(const float4*)&attr[(size_t)e * 64 + s * 32 + l4 * 8];
    q[s * 2 + 1] = *(const float4*)&attr[(size_t)e * 64 + s * 32 + l4 * 8 + 4];
  }
  f32x4 acc[8];
  #pragma unroll
  for (int m = 0; m < 8; ++m) acc[m] = (f32x4){0.f, 0.f, 0.f, 0.f};
  #pragma unroll
  for (int s = 0; s < 2; ++s) {
    short8 bt;
    bt[0] = (short)f2bf(q[s * 2].x); bt[1] = (short)f2bf(q[s * 2].y);
    bt[2] = (short)f2bf(q[s * 2].z); bt[3] = (short)f2bf(q[s * 2].w);
    bt[4] = (short)f2bf(q[s * 2 + 1].x); bt[5] = (short)f2bf(q[s * 2 + 1].y);
    bt[6] = (short)f2bf(q[s * 2 + 1].z); bt[7] = (short)f2bf(q[s * 2 + 1].w);
    #pragma unroll
    for (int m = 0; m < 8; ++m) {
      const short8 af = *(const short8*)&Web[(m * 16 + l15) * 64 + s * 32 + l4 * 8];
      acc[m] = __builtin_amdgcn_mfma_f32_16x16x32_bf16(af, bt, acc[m], 0, 0, 0);
    }
  }
  const bool ok = (e0 < E);
  #pragma unroll
  for (int m = 0; m < 8; ++m) {
    ushort4 pk;
    pk.x = f2bf(fmaxf(xr[m].x + acc[m][0], 0.f));
    pk.y = f2bf(fmaxf(xr[m].y + acc[m][1], 0.f));
    pk.z = f2bf(fmaxf(xr[m].z + acc[m][2], 0.f));
    pk.w = f2bf(fmaxf(xr[m].w + acc[m][3], 0.f));
    if (ok) *(ushort4*)&msg[(size_t)p * 128 + m * 16 + l4 * 4] = pk;
  }
}

// ---------- aggr: sequential CSR segment-sum, uint2 per thread ----------
// thread = (node, 4-channel group). N*32 threads.
__global__ __launch_bounds__(256) void aggr_kernel(
    const float* __restrict__ x, const int* __restrict__ off,
    const int* __restrict__ cnt, const uint2* __restrict__ msg2,
    uint2* __restrict__ U, int N) {
  const int idx = blockIdx.x * 256 + threadIdx.x;
  if (idx >= N * 32) return;
  const int n = idx >> 5, d = idx & 31;
  const int o = off[n], c = cnt[n];
  float s0 = 0.f, s1 = 0.f, s2 = 0.f, s3 = 0.f;
  float r0 = 0.f, r1 = 0.f, r2 = 0.f, r3 = 0.f;
  const uint2* p = msg2 + (size_t)o * 32 + d;
  int q = 0;
  for (; q + 4 <= c; q += 4) {
    const uint2 m0 = p[0], m1 = p[32], m2 = p[64], m3 = p[96];
    s0 += __uint_as_float(m0.x << 16) + __uint_as_float(m1.x << 16);
    s1 += __uint_as_float(m0.x & 0xffff0000u) + __uint_as_float(m1.x & 0xffff0000u);
    s2 += __uint_as_float(m0.y << 16) + __uint_as_float(m1.y << 16);
    s3 += __uint_as_float(m0.y & 0xffff0000u) + __uint_as_float(m1.y & 0xffff0000u);
    r0 += __uint_as_float(m2.x << 16) + __uint_as_float(m3.x << 16);
    r1 += __uint_as_float(m2.x & 0xffff0000u) + __uint_as_float(m3.x & 0xffff0000u);
    r2 += __uint_as_float(m2.y << 16) + __uint_as_float(m3.y << 16);
    r3 += __uint_as_float(m2.y & 0xffff0000u) + __uint_as_float(m3.y & 0xffff0000u);
    p += 128;
  }
  for (; q < c; ++q) {
    const uint2 mm = p[0];
    s0 += __uint_as_float(mm.x << 16);
    s1 += __uint_as_float(mm.x & 0xffff0000u);
    s2 += __uint_as_float(mm.y << 16);
    s3 += __uint_as_float(mm.y & 0xffff0000u);
    p += 32;
  }
  const float4 xv = *(const float4*)&x[(size_t)n * 128 + d * 4];
  const float u0 = fmaf(1.00001f, xv.x, s0 + r0);
  const float u1 = fmaf(1.00001f, xv.y, s1 + r1);
  const float u2 = fmaf(1.00001f, xv.z, s2 + r2);
  const float u3 = fmaf(1.00001f, xv.w, s3 + r3);
  uint2 out;
  out.x = ((unsigned int)f2bf(u1) << 16) | f2bf(u0);
  out.y = ((unsigned int)f2bf(u3) << 16) | f2bf(u2);
  U[(size_t)n * 32 + d] = out;
}

// ---------- streaming MFMA node GEMMs, no LDS ----------
__global__ __launch_bounds__(256) void gemm_kernel(
    const float* __restrict__ x, const unsigned short* __restrict__ Ub,
    const unsigned short* __restrict__ Wnb, const unsigned short* __restrict__ Wrb,
    const float* __restrict__ b_nn, float* __restrict__ out, int N) {
  const int lane = threadIdx.x & 63;
  const int l15 = lane & 15, l4 = lane >> 4;
  const int gw = (blockIdx.x * 256 + threadIdx.x) >> 6;
  const int ntiles = (N + 15) >> 4;
  if (gw >= ntiles) return;
  const int n0 = gw * 16 + l15;
  const int n = (n0 < N) ? n0 : (N - 1);
  short8 bu[4], bx[4];
  #pragma unroll
  for (int s = 0; s < 4; ++s) {
    bu[s] = *(const short8*)&Ub[(size_t)n * 128 + s * 32 + l4 * 8];
    const float4 q0 = *(const float4*)&x[(size_t)n * 128 + s * 32 + l4 * 8];
    const float4 q1 = *(const float4*)&x[(size_t)n * 128 + s * 32 + l4 * 8 + 4];
    short8 bt;
    bt[0] = (short)f2bf(q0.x); bt[1] = (short)f2bf(q0.y);
    bt[2] = (short)f2bf(q0.z); bt[3] = (short)f2bf(q0.w);
    bt[4] = (short)f2bf(q1.x); bt[5] = (short)f2bf(q1.y);
    bt[6] = (short)f2bf(q1.z); bt[7] = (short)f2bf(q1.w);
    bx[s] = bt;
  }
  const bool ok = (n0 < N);
  #pragma unroll
  for (int m = 0; m < 8; ++m) {
    f32x4 an = (f32x4){0.f, 0.f, 0.f, 0.f};
    f32x4 ar = (f32x4){0.f, 0.f, 0.f, 0.f};
    #pragma unroll
    for (int s = 0; s < 4; ++s) {
      const short8 wn = *(const short8*)&Wnb[(m * 16 + l15) * 128 + s * 32 + l4 * 8];
      const short8 wr = *(const short8*)&Wrb[(m * 16 + l15) * 128 + s * 32 + l4 * 8];
      an = __builtin_amdgcn_mfma_f32_16x16x32_bf16(wn, bu[s], an, 0, 0, 0);
      ar = __builtin_amdgcn_mfma_f32_16x16x32_bf16(wr, bx[s], ar, 0, 0, 0);
    }
    const float4 bb = *(const float4*)&b_nn[m * 16 + l4 * 4];
    float4 o4;
    o4.x = (fmaxf(an[0] + bb.x, 0.f) + ar[0]) * INV_SQRT2;
    o4.y = (fmaxf(an[1] + bb.y, 0.f) + ar[1]) * INV_SQRT2;
    o4.z = (fmaxf(an[2] + bb.z, 0.f) + ar[2]) * INV_SQRT2;
    o4.w = (fmaxf(an[3] + bb.w, 0.f) + ar[3]) * INV_SQRT2;
    if (ok) *(float4*)&out[(size_t)n0 * 128 + m * 16 + l4 * 4] = o4;
  }
}

// ---------- legacy fallback (round-1 path, atomics) ----------
__global__ __launch_bounds__(256) void edge_kernel_legacy(
    const float* __restrict__ x, const int* __restrict__ ei,
    const float* __restrict__ edge_attr, const float* __restrict__ W_edge,
    float* aggr, int E) {
  __shared__ float Wl[64 * 128];
  __shared__ float Al[32 * 64];
  const int tid = threadIdx.x;
  for (int idx = tid; idx < 128 * 64; idx += 256) {
    int o = idx >> 6, k = idx & 63;
    Wl[k * 128 + o] = W_edge[idx];
  }
  const int og = tid & 31;
  const int er = tid >> 5;
  const int ntiles = (E + 31) >> 5;
  for (int tile = blockIdx.x; tile < ntiles; tile += gridDim.x) {
    __syncthreads();
    {
      const float* src_ptr = edge_attr + (size_t)tile * 32 * 64;
      const int limit = E * 64 - tile * 32 * 64;
      for (int idx = tid; idx < 2048; idx += 256)
        Al[idx] = (idx < limit) ? src_ptr[idx] : 0.f;
    }
    __syncthreads();
    float acc[4][4] = {};
    #pragma unroll 4
    for (int k = 0; k < 64; ++k) {
      const float4 w = *(const float4*)&Wl[k * 128 + og * 4];
      #pragma unroll
      for (int j = 0; j < 4; ++j) {
        const float a = Al[(er * 4 + j) * 64 + k];
        acc[j][0] = fmaf(a, w.x, acc[j][0]);
        acc[j][1] = fmaf(a, w.y, acc[j][1]);
        acc[j][2] = fmaf(a, w.z, acc[j][2]);
        acc[j][3] = fmaf(a, w.w, acc[j][3]);
      }
    }
    #pragma unroll
    for (int j = 0; j < 4; ++j) {
      const int e = tile * 32 + er * 4 + j;
      if (e < E) {
        const int s = ei[e];
        const int d = ei[E + e];
        const float4 xv = *(const float4*)&x[(size_t)s * 128 + og * 4];
        float* ap = aggr + (size_t)d * 128 + og * 4;
        atomicAdd(ap + 0, fmaxf(xv.x + acc[j][0], 0.f));
        atomicAdd(ap + 1, fmaxf(xv.y + acc[j][1], 0.f));
        atomicAdd(ap + 2, fmaxf(xv.z + acc[j][2], 0.f));
        atomicAdd(ap + 3, fmaxf(xv.w + acc[j][3], 0.f));
      }
    }
  }
}

__global__ __launch_bounds__(256) void node_kernel_legacy(
    const float* __restrict__ x, const float* __restrict__ WT,
    const float* __restrict__ b_nn, float* io, int N) {
  __shared__ float Ul[16 * 128];
  __shared__ float Xl[16 * 128];
  const int tid = threadIdx.x;
  const int og = tid & 31;
  const int nr = tid >> 5;
  const float* WnnT = WT;
  const float* WresT = WT + 128 * 128;
  const int ntiles = (N + 15) >> 4;
  for (int tile = blockIdx.x; tile < ntiles; tile += gridDim.x) {
    __syncthreads();
    {
      const size_t base = (size_t)tile * 16 * 128;
      const int limit = N * 128 - (int)base;
      for (int idx = tid; idx < 2048; idx += 256) {
        const float xv = (idx < limit) ? x[base + idx] : 0.f;
        const float av = (idx < limit) ? io[base + idx] : 0.f;
        Xl[idx] = xv;
        Ul[idx] = fmaf(1.00001f, xv, av);
      }
    }
    __syncthreads();
    float accn[2][4] = {}, accr[2][4] = {};
    #pragma unroll 4
    for (int kk = 0; kk < 128; ++kk) {
      const float4 wn = *(const float4*)&WnnT[kk * 128 + og * 4];
      const float4 wr = *(const float4*)&WresT[kk * 128 + og * 4];
      #pragma unroll
      for (int j = 0; j < 2; ++j) {
        const float u = Ul[(nr * 2 + j) * 128 + kk];
        const float xx = Xl[(nr * 2 + j) * 128 + kk];
        accn[j][0] = fmaf(u, wn.x, accn[j][0]);
        accn[j][1] = fmaf(u, wn.y, accn[j][1]);
        accn[j][2] = fmaf(u, wn.z, accn[j][2]);
        accn[j][3] = fmaf(u, wn.w, accn[j][3]);
        accr[j][0] = fmaf(xx, wr.x, accr[j][0]);
        accr[j][1] = fmaf(xx, wr.y, accr[j][1]);
        accr[j][2] = fmaf(xx, wr.z, accr[j][2]);
        accr[j][3] = fmaf(xx, wr.w, accr[j][3]);
      }
    }
    const float4 b = *(const float4*)&b_nn[og * 4];
    #pragma unroll
    for (int j = 0; j < 2; ++j) {
      const int n = tile * 16 + nr * 2 + j;
      if (n < N) {
        float4 o4;
        o4.x = (fmaxf(accn[j][0] + b.x, 0.f) + accr[j][0]) * INV_SQRT2;
        o4.y = (fmaxf(accn[j][1] + b.y, 0.f) + accr[j][1]) * INV_SQRT2;
        o4.z = (fmaxf(accn[j][2] + b.z, 0.f) + accr[j][2]) * INV_SQRT2;
        o4.w = (fmaxf(accn[j][3] + b.w, 0.f) + accr[j][3]) * INV_SQRT2;
        *(float4*)&io[(size_t)n * 128 + og * 4] = o4;
      }
    }
  }
}

extern "C" void kernel_launch(void* const* d_in, const int* in_sizes, int n_in,
                              void* d_out, int out_size, void* d_ws, size_t ws_size,
                              hipStream_t stream) {
  const float* x      = (const float*)d_in[0];
  const int*   ei     = (const int*)d_in[1];
  const float* ea     = (const float*)d_in[2];
  const float* W_edge = (const float*)d_in[3];
  const float* W_nn   = (const float*)d_in[4];
  const float* b_nn   = (const float*)d_in[5];
  const float* W_res  = (const float*)d_in[6];
  float* out = (float*)d_out;
  const int N = in_sizes[0] / 128;
  const int E = in_sizes[2] / 64;

  char* ws = (char*)d_ws;
  const size_t WT_OFF   = 0;                                  // 131072 B
  const size_t WEB_OFF  = 131072;
  const size_t WNB_OFF  = WEB_OFF + 16384;
  const size_t WRB_OFF  = WNB_OFF + 32768;
  const size_t CNT_OFF  = WRB_OFF + 32768;                    // N ints
  const size_t OFF_OFF  = CNT_OFF + (size_t)N * 4;
  const size_t CUR_OFF  = OFF_OFF + (size_t)N * 4;
  const size_t BSUM_OFF = CUR_OFF + (size_t)N * 4;
  const size_t MSG_OFF  = (BSUM_OFF + 2048 + 255) & ~(size_t)255;
  const size_t U_OFF    = (MSG_OFF + (size_t)E * 256 + 255) & ~(size_t)255;
  const size_t NEED     = U_OFF + (size_t)N * 256;

  float* WT = (float*)(ws + WT_OFF);
  unsigned short* Web = (unsigned short*)(ws + WEB_OFF);
  unsigned short* Wnb = (unsigned short*)(ws + WNB_OFF);
  unsigned short* Wrb = (unsigned short*)(ws + WRB_OFF);
  prep_kernel<<<64, 256, 0, stream>>>(W_edge, W_nn, W_res, WT, Web, Wnb, Wrb);

  if (ws_size >= NEED) {
    int* cnt  = (int*)(ws + CNT_OFF);
    int* off  = (int*)(ws + OFF_OFF);
    int* cur  = (int*)(ws + CUR_OFF);
    int* bsum = (int*)(ws + BSUM_OFF);
    unsigned short* msg = (unsigned short*)(ws + MSG_OFF);
    uint2* U = (uint2*)(ws + U_OFF);

    const int nb = (N + 255) / 256;   // <= 512
    hipMemsetAsync(cnt, 0, (size_t)N * 4, stream);
    hist_kernel<<<(E + 255) / 256, 256, 0, stream>>>(ei, cnt, E);
    scan1_kernel<<<nb, 256, 0, stream>>>(cnt, off, bsum, N);
    scan2_kernel<<<1, 512, 0, stream>>>(bsum, nb);
    scan3_kernel<<<nb, 256, 0, stream>>>(off, cur, bsum, N);

    const int etiles = (E + 15) / 16;
    msg_mfma_kernel<<<(etiles + 3) / 4, 256, 0, stream>>>(
        x, ei, cur, ea, Web, msg, E);

    aggr_kernel<<<(N * 32 + 255) / 256, 256, 0, stream>>>(
        x, off, cnt, (const uint2*)msg, U, N);

    const int ntilesn = (N + 15) / 16;
    gemm_kernel<<<(ntilesn + 3) / 4, 256, 0, stream>>>(
        x, (const unsigned short*)U, Wnb, Wrb, b_nn, out, N);
  } else {
    hipMemsetAsync(d_out, 0, (size_t)N * 128 * sizeof(float), stream);
    const int etiles = (E + 31) / 32;
    edge_kernel_legacy<<<(etiles < 4096 ? etiles : 4096), 256, 0, stream>>>(
        x, ei, ea, W_edge, out, E);
    const int ntiles = (N + 15) / 16;
    node_kernel_legacy<<<(ntiles < 2048 ? ntiles : 2048), 256, 0, stream>>>(
        x, WT, b_nn, out, N);
  }
}